// Round 1
// baseline (243.581 us; speedup 1.0000x reference)
//
#include <hip/hip_runtime.h>

// Problem constants (match reference)
constexpr int B = 8, C = 256, H = 96, W = 96;
constexpr int HW = H * W;          // 9216
constexpr int NPIX = B * HW;       // 73728
constexpr int PATCH = 21;
constexpr int HALF = PATCH / 2;    // 10
constexpr int DIL = 2;
constexpr int P2 = PATCH * PATCH;  // 441

// Stage 1: D[b,y,x] = sum_c in1[b,c,y,x] * in2[b,c,y,x]
// One thread per pixel; channel stride is HW floats, so for a fixed c the
// wave's 64 lanes read 64 consecutive floats -> fully coalesced 256B/load.
__global__ __launch_bounds__(256) void dot_kernel(const float* __restrict__ a,
                                                  const float* __restrict__ b,
                                                  float* __restrict__ D) {
    int pix = blockIdx.x * blockDim.x + threadIdx.x;
    if (pix >= NPIX) return;
    int bb = pix / HW;
    int hw = pix - bb * HW;
    const float* pa = a + (size_t)bb * C * HW + hw;
    const float* pb = b + (size_t)bb * C * HW + hw;
    // 4 independent accumulators to expose ILP / keep many loads in flight.
    float acc0 = 0.f, acc1 = 0.f, acc2 = 0.f, acc3 = 0.f;
    #pragma unroll 4
    for (int c = 0; c < C; c += 4) {
        float a0 = pa[(size_t)(c + 0) * HW];
        float a1 = pa[(size_t)(c + 1) * HW];
        float a2 = pa[(size_t)(c + 2) * HW];
        float a3 = pa[(size_t)(c + 3) * HW];
        float b0 = pb[(size_t)(c + 0) * HW];
        float b1 = pb[(size_t)(c + 1) * HW];
        float b2 = pb[(size_t)(c + 2) * HW];
        float b3 = pb[(size_t)(c + 3) * HW];
        acc0 = fmaf(a0, b0, acc0);
        acc1 = fmaf(a1, b1, acc1);
        acc2 = fmaf(a2, b2, acc2);
        acc3 = fmaf(a3, b3, acc3);
    }
    D[pix] = (acc0 + acc1) + (acc2 + acc3);
}

// Stage 2: out[b, py*21+px, y, x] = D[b, y+(py-10)*2, x+(px-10)*2] (0 if OOB)
// One thread per 4 consecutive output x -> float4 coalesced store.
// D reads are cache-resident (D is 295 KB total, 37 KB per batch image).
__global__ __launch_bounds__(256) void scatter_kernel(const float* __restrict__ D,
                                                      float* __restrict__ out) {
    constexpr int W4 = W / 4;                    // 24
    constexpr int TOTAL = B * P2 * H * W4;       // 8,128,512
    int tid = blockIdx.x * blockDim.x + threadIdx.x;
    if (tid >= TOTAL) return;

    int x4 = tid % W4;
    int t  = tid / W4;
    int y  = t % H;  t /= H;
    int p  = t % P2; t /= P2;
    int bb = t;

    int py = p / PATCH;
    int px = p - py * PATCH;
    int sy = y + (py - HALF) * DIL;
    int x0 = x4 * 4;
    int sx0 = x0 + (px - HALF) * DIL;

    float4 v = make_float4(0.f, 0.f, 0.f, 0.f);
    if (sy >= 0 && sy < H) {
        const float* row = D + (size_t)(bb * H + sy) * W;
        if (sx0 >= 0 && sx0 + 3 < W) {
            // fully in-bounds: two aligned float2 loads (sx0 is always even)
            float2 lo = *(const float2*)(row + sx0);
            float2 hi = *(const float2*)(row + sx0 + 2);
            v = make_float4(lo.x, lo.y, hi.x, hi.y);
        } else {
            float* pv = &v.x;
            #pragma unroll
            for (int i = 0; i < 4; ++i) {
                int sx = sx0 + i;
                if (sx >= 0 && sx < W) pv[i] = row[sx];
            }
        }
    }
    // out linear index of element 0 is exactly tid*4 (decode order matches layout)
    reinterpret_cast<float4*>(out)[tid] = v;
}

extern "C" void kernel_launch(void* const* d_in, const int* in_sizes, int n_in,
                              void* d_out, int out_size, void* d_ws, size_t ws_size,
                              hipStream_t stream) {
    const float* in1 = (const float*)d_in[0];
    const float* in2 = (const float*)d_in[1];
    float* out = (float*)d_out;
    float* D = (float*)d_ws;  // NPIX floats = 294,912 bytes

    {
        int threads = 256;
        int blocks = (NPIX + threads - 1) / threads;  // 288
        dot_kernel<<<blocks, threads, 0, stream>>>(in1, in2, D);
    }
    {
        constexpr int TOTAL = B * P2 * H * (W / 4);
        int threads = 256;
        int blocks = (TOTAL + threads - 1) / threads;  // 31752
        scatter_kernel<<<blocks, threads, 0, stream>>>(D, out);
    }
}